// Round 4
// baseline (180.238 us; speedup 1.0000x reference)
//
#include <hip/hip_runtime.h>
#include <stdint.h>
#include <stddef.h>

typedef __bf16 bf16x8 __attribute__((ext_vector_type(8)));
typedef float f32x4 __attribute__((ext_vector_type(4)));
typedef float f32x16 __attribute__((ext_vector_type(16)));
typedef int int4v __attribute__((ext_vector_type(4)));
typedef unsigned short u16;
typedef unsigned int u32;

__device__ __forceinline__ u16 f2bf(float f) {
    union { float f; unsigned u; } x; x.f = f;
    unsigned r = x.u + 0x7fffu + ((x.u >> 16) & 1u);
    return (u16)(r >> 16);
}

__device__ __forceinline__ float fexp2(float x) { return __builtin_amdgcn_exp2f(x); }

__device__ __forceinline__ u32 cvtpk(float lo, float hi) {
    u32 r;
    asm("v_cvt_pk_bf16_f32 %0, %1, %2" : "=v"(r) : "v"(lo), "v"(hi));
    return r;
}

__device__ __forceinline__ void perm32swap(u32& a, u32& b) {
    asm("v_permlane32_swap_b32 %0, %1" : "+v"(a), "+v"(b));
}

__device__ __forceinline__ f32x16 mfma32(bf16x8 a, bf16x8 b, f32x16 c) {
    return __builtin_amdgcn_mfma_f32_32x32x16_bf16(a, b, c, 0, 0, 0);
}

// ---------- all 4 weight transposes in one launch ----------
__global__ __launch_bounds__(256) void wtrans4(
        const float* __restrict__ Wq, const float* __restrict__ Wk,
        const float* __restrict__ Wv, const float* __restrict__ Wo,
        u16* __restrict__ oq, u16* __restrict__ ok,
        u16* __restrict__ ov, u16* __restrict__ oo) {
    const int z = blockIdx.z;
    const float* W = (z == 0) ? Wq : (z == 1) ? Wk : (z == 2) ? Wv : Wo;
    u16* O = (z == 0) ? oq : (z == 1) ? ok : (z == 2) ? ov : oo;
    int n = blockIdx.x * 16 + (threadIdx.x >> 4);
    int k = blockIdx.y * 16 + (threadIdx.x & 15);
    O[(size_t)n * 512 + k] = f2bf(W[(size_t)k * 512 + n]);
}

// ---------- fused QKV GEMM ----------
__global__ __launch_bounds__(256) void gemm_qkv(
        const float* __restrict__ hidden, const float* __restrict__ enc,
        const u16* __restrict__ wq, const u16* __restrict__ wk, const u16* __restrict__ wv,
        u16* __restrict__ qo, u16* __restrict__ ko, u16* __restrict__ vo) {
    __shared__ __align__(16) u16 As[128 * 64];
    __shared__ __align__(16) u16 Bs[64 * 64];
    const int z = blockIdx.z;
    const float* A = (z == 0) ? hidden : enc;
    const u16* Bt = (z == 0) ? wq : (z == 1) ? wk : wv;
    const int tid = threadIdx.x, lane = tid & 63, wave = tid >> 6;
    const int wr = (wave >> 1) * 64, wc = (wave & 1) * 32;
    const int brow = blockIdx.x * 128, bcol = blockIdx.y * 64;
    const int lrow = lane & 15;

    f32x4 acc[4][2] = {};

    for (int k0 = 0; k0 < 512; k0 += 64) {
#pragma unroll
        for (int i = 0; i < 4; ++i) {
            int g = i * 256 + tid;
            int r = g >> 3, gc = g & 7;
            const float* src = A + (size_t)(brow + r) * 512 + k0 + gc * 8;
            float4 f0 = *(const float4*)src, f1 = *(const float4*)(src + 4);
            int4v w;
            w[0] = cvtpk(f0.x, f0.y); w[1] = cvtpk(f0.z, f0.w);
            w[2] = cvtpk(f1.x, f1.y); w[3] = cvtpk(f1.z, f1.w);
            *(int4v*)((char*)As + r * 128 + ((gc ^ (r & 7)) << 4)) = w;
        }
#pragma unroll
        for (int i = 0; i < 2; ++i) {
            int g = i * 256 + tid;
            int r = g >> 3, gc = g & 7;
            const u16* src = Bt + (size_t)(bcol + r) * 512 + k0 + gc * 8;
            *(int4v*)((char*)Bs + r * 128 + ((gc ^ (r & 7)) << 4)) = *(const int4v*)src;
        }
        __syncthreads();
#pragma unroll
        for (int kc = 0; kc < 2; ++kc) {
            const int kg = kc * 4 + (lane >> 4);
            bf16x8 af[4], bfr[2];
#pragma unroll
            for (int m = 0; m < 4; ++m) {
                int r = wr + m * 16 + lrow;
                af[m] = *(const bf16x8*)((char*)As + r * 128 + ((kg ^ (r & 7)) << 4));
            }
#pragma unroll
            for (int n = 0; n < 2; ++n) {
                int r = wc + n * 16 + lrow;
                bfr[n] = *(const bf16x8*)((char*)Bs + r * 128 + ((kg ^ (r & 7)) << 4));
            }
#pragma unroll
            for (int m = 0; m < 4; ++m)
#pragma unroll
                for (int n = 0; n < 2; ++n)
                    acc[m][n] = __builtin_amdgcn_mfma_f32_16x16x32_bf16(af[m], bfr[n], acc[m][n], 0, 0, 0);
        }
        __syncthreads();
    }

#pragma unroll
    for (int m = 0; m < 4; ++m) {
        int gr0 = brow + wr + m * 16 + ((lane >> 4) << 2);
#pragma unroll
        for (int n = 0; n < 2; ++n) {
            int gc = bcol + wc + n * 16 + lrow;
            int hh = gc >> 6, d = gc & 63;
            if (z == 2) {
                int b = gr0 >> 11, mm = gr0 & 2047;
                ushort4 pk;
                pk.x = f2bf(acc[m][n][0]); pk.y = f2bf(acc[m][n][1]);
                pk.z = f2bf(acc[m][n][2]); pk.w = f2bf(acc[m][n][3]);
                *(ushort4*)(vo + ((size_t)(b * 8 + hh) * 64 + d) * 2048 + mm) = pk;
            } else {
                u16* dst = (z == 0) ? qo : ko;
                const float s = (z == 0) ? 0.125f * 1.44269504f : 1.0f;
#pragma unroll
                for (int j = 0; j < 4; ++j) {
                    int gr = gr0 + j;
                    int b = gr >> 11, nn = gr & 2047;
                    dst[((size_t)(b * 8 + hh) * 2048 + nn) * 64 + d] = f2bf(acc[m][n][j] * s);
                }
            }
        }
    }
}

// ---------- output GEMM: out[8192][512] = at_bf @ Wo^T + bo ----------
__global__ __launch_bounds__(256) void gemm_out(
        const u16* __restrict__ A, const u16* __restrict__ Bt,
        const float* __restrict__ bias, float* __restrict__ out) {
    __shared__ __align__(16) u16 As[128 * 64];
    __shared__ __align__(16) u16 Bs[64 * 64];
    const int tid = threadIdx.x, lane = tid & 63, wave = tid >> 6;
    const int wr = (wave >> 1) * 64, wc = (wave & 1) * 32;
    const int brow = blockIdx.x * 128, bcol = blockIdx.y * 64;
    const int lrow = lane & 15;

    f32x4 acc[4][2] = {};

    for (int k0 = 0; k0 < 512; k0 += 64) {
#pragma unroll
        for (int i = 0; i < 4; ++i) {
            int g = i * 256 + tid;
            int r = g >> 3, gc = g & 7;
            const u16* src = A + (size_t)(brow + r) * 512 + k0 + gc * 8;
            *(int4v*)((char*)As + r * 128 + ((gc ^ (r & 7)) << 4)) = *(const int4v*)src;
        }
#pragma unroll
        for (int i = 0; i < 2; ++i) {
            int g = i * 256 + tid;
            int r = g >> 3, gc = g & 7;
            const u16* src = Bt + (size_t)(bcol + r) * 512 + k0 + gc * 8;
            *(int4v*)((char*)Bs + r * 128 + ((gc ^ (r & 7)) << 4)) = *(const int4v*)src;
        }
        __syncthreads();
#pragma unroll
        for (int kc = 0; kc < 2; ++kc) {
            const int kg = kc * 4 + (lane >> 4);
            bf16x8 af[4], bfr[2];
#pragma unroll
            for (int m = 0; m < 4; ++m) {
                int r = wr + m * 16 + lrow;
                af[m] = *(const bf16x8*)((char*)As + r * 128 + ((kg ^ (r & 7)) << 4));
            }
#pragma unroll
            for (int n = 0; n < 2; ++n) {
                int r = wc + n * 16 + lrow;
                bfr[n] = *(const bf16x8*)((char*)Bs + r * 128 + ((kg ^ (r & 7)) << 4));
            }
#pragma unroll
            for (int m = 0; m < 4; ++m)
#pragma unroll
                for (int n = 0; n < 2; ++n)
                    acc[m][n] = __builtin_amdgcn_mfma_f32_16x16x32_bf16(af[m], bfr[n], acc[m][n], 0, 0, 0);
        }
        __syncthreads();
    }

#pragma unroll
    for (int m = 0; m < 4; ++m) {
        int gr0 = brow + wr + m * 16 + ((lane >> 4) << 2);
#pragma unroll
        for (int n = 0; n < 2; ++n) {
            int gc = bcol + wc + n * 16 + lrow;
            float bv = bias[gc];
#pragma unroll
            for (int j = 0; j < 4; ++j)
                out[(size_t)(gr0 + j) * 512 + gc] = acc[m][n][j] + bv;
        }
    }
}

// ---------- flash attention v3: zero-LDS, zero-barrier, reg-dbuf ----------
// 512 blocks x 256 thr (4 waves x 32 q); XCD-swizzled so each XCD sees 4 bh.
// K and VT fragments loaded straight from global (L2-resident per XCD).
// ST = K.Q^T (lane holds 32 P for q=lane&31); no-max softmax (log2e in Q);
// PV: O^T = VT.P^T with B-frag built via cvt_pk + permlane32_swap.
__global__ __launch_bounds__(256) void flash_attn(
        const u16* __restrict__ Q, const u16* __restrict__ K,
        const u16* __restrict__ VT, u16* __restrict__ Oa) {
    const int tid  = threadIdx.x;
    const int lane = tid & 63;
    const int wave = tid >> 6;
    const int bid  = blockIdx.x;
    const int lid  = (bid & 7) * 64 + (bid >> 3);   // bijective XCD swizzle (512 = 8*64)
    const int bh   = lid >> 4;
    const int qt   = lid & 15;
    const int ql   = lane & 31;
    const int h    = lane >> 5;
    const int qg   = qt * 128 + wave * 32 + ql;

    // Q b-frags (pre-scaled by 0.125*log2e in gemm_qkv)
    const u16* qp = Q + ((size_t)bh * 2048 + qg) * 64 + 8 * h;
    bf16x8 qf[4];
#pragma unroll
    for (int kc = 0; kc < 4; ++kc) qf[kc] = *(const bf16x8*)(qp + 16 * kc);

    // per-lane fragment base pointers (advance per tile)
    const u16* kp0 = K  + ((size_t)bh * 2048 + ql) * 64 + 8 * h;        // kv rows 0..31
    const u16* kp1 = kp0 + 32 * 64;                                      // kv rows 32..63
    const u16* vp0 = VT + ((size_t)bh * 64 + ql) * 2048 + 8 * h;        // d 0..31
    const u16* vp1 = vp0 + 32 * 2048;                                    // d 32..63

#define LOADT(K0, K1, V0, V1, T) do { \
    const u16* kt0 = kp0 + (size_t)(T) * 4096; \
    const u16* kt1 = kp1 + (size_t)(T) * 4096; \
    const u16* vt0 = vp0 + (T) * 64; \
    const u16* vt1 = vp1 + (T) * 64; \
    _Pragma("unroll") \
    for (int kc = 0; kc < 4; ++kc) { \
        K0[kc] = *(const bf16x8*)(kt0 + kc * 16); \
        K1[kc] = *(const bf16x8*)(kt1 + kc * 16); \
        V0[kc] = *(const bf16x8*)(vt0 + kc * 16); \
        V1[kc] = *(const bf16x8*)(vt1 + kc * 16); \
    } \
} while (0)

#define PP(i) ((i) < 16 ? st0[(i) & 15] : st1[(i) & 15])
#define COMPUTE(K0, K1, V0, V1) do { \
    f32x16 st0 = {}, st1 = {}; \
    __builtin_amdgcn_s_setprio(1); \
    _Pragma("unroll") \
    for (int kc = 0; kc < 4; ++kc) { \
        st0 = mfma32(K0[kc], qf[kc], st0); \
        st1 = mfma32(K1[kc], qf[kc], st1); \
    } \
    __builtin_amdgcn_s_setprio(0); \
    _Pragma("unroll") \
    for (int r = 0; r < 16; r += 4) { \
        st0[r]   = fexp2(st0[r]);   ls0 += st0[r]; \
        st0[r+1] = fexp2(st0[r+1]); ls1 += st0[r+1]; \
        st0[r+2] = fexp2(st0[r+2]); ls2 += st0[r+2]; \
        st0[r+3] = fexp2(st0[r+3]); ls3 += st0[r+3]; \
    } \
    _Pragma("unroll") \
    for (int r = 0; r < 16; r += 4) { \
        st1[r]   = fexp2(st1[r]);   ls0 += st1[r]; \
        st1[r+1] = fexp2(st1[r+1]); ls1 += st1[r+1]; \
        st1[r+2] = fexp2(st1[r+2]); ls2 += st1[r+2]; \
        st1[r+3] = fexp2(st1[r+3]); ls3 += st1[r+3]; \
    } \
    __builtin_amdgcn_s_setprio(1); \
    _Pragma("unroll") \
    for (int kc = 0; kc < 4; ++kc) { \
        u32 A0 = cvtpk(PP(8 * kc + 0), PP(8 * kc + 1)); \
        u32 A1 = cvtpk(PP(8 * kc + 2), PP(8 * kc + 3)); \
        u32 B0 = cvtpk(PP(8 * kc + 4), PP(8 * kc + 5)); \
        u32 B1 = cvtpk(PP(8 * kc + 6), PP(8 * kc + 7)); \
        perm32swap(A0, B0); \
        perm32swap(A1, B1); \
        union { bf16x8 v; u32 u[4]; } bb; \
        bb.u[0] = A0; bb.u[1] = A1; bb.u[2] = B0; bb.u[3] = B1; \
        acc0 = mfma32(V0[kc], bb.v, acc0); \
        acc1 = mfma32(V1[kc], bb.v, acc1); \
    } \
    __builtin_amdgcn_s_setprio(0); \
} while (0)

    f32x16 acc0 = {}, acc1 = {};
    float ls0 = 0.f, ls1 = 0.f, ls2 = 0.f, ls3 = 0.f;

    bf16x8 kA0[4], kA1[4], vA0[4], vA1[4];
    bf16x8 kB0[4], kB1[4], vB0[4], vB1[4];

    LOADT(kA0, kA1, vA0, vA1, 0);
    for (int t = 0; t < 32; t += 2) {
        LOADT(kB0, kB1, vB0, vB1, t + 1);
        COMPUTE(kA0, kA1, vA0, vA1);
        if (t + 2 < 32) LOADT(kA0, kA1, vA0, vA1, t + 2);
        COMPUTE(kB0, kB1, vB0, vB1);
    }
#undef PP
#undef COMPUTE
#undef LOADT

    float lsum = (ls0 + ls1) + (ls2 + ls3);
    lsum += __shfl_xor(lsum, 32);
    float inv = 1.0f / lsum;

    // O^T[d][q]: q = lane&31, d = 32*db + 8*rg + 4*h + (reg&3)
    int b = bh >> 3, hd = bh & 7;
    u16* orow = Oa + ((size_t)b * 2048 + qg) * 512 + hd * 64;
#pragma unroll
    for (int db = 0; db < 2; ++db) {
        const f32x16 a = db ? acc1 : acc0;
#pragma unroll
        for (int rg = 0; rg < 4; ++rg) {
            int d0 = db * 32 + rg * 8 + h * 4;
            ushort4 pk;
            pk.x = f2bf(a[rg * 4 + 0] * inv);
            pk.y = f2bf(a[rg * 4 + 1] * inv);
            pk.z = f2bf(a[rg * 4 + 2] * inv);
            pk.w = f2bf(a[rg * 4 + 3] * inv);
            *(ushort4*)(orow + d0) = pk;
        }
    }
}

extern "C" void kernel_launch(void* const* d_in, const int* in_sizes, int n_in,
                              void* d_out, int out_size, void* d_ws, size_t ws_size,
                              hipStream_t stream) {
    const float* hidden = (const float*)d_in[0];
    const float* enc    = (const float*)d_in[1];
    const float* Wq     = (const float*)d_in[2];
    const float* Wk     = (const float*)d_in[3];
    const float* Wv     = (const float*)d_in[4];
    const float* Wo     = (const float*)d_in[5];
    const float* bo     = (const float*)d_in[6];
    float* out = (float*)d_out;

    char* ws = (char*)d_ws;
    const size_t MB = 1ull << 20;
    u16* q_bf  = (u16*)(ws + 0 * MB);   // [B,H,N,dh] (pre-scaled 0.125*log2e)
    u16* k_bf  = (u16*)(ws + 8 * MB);   // [B,H,M,dh]
    u16* vt_bf = (u16*)(ws + 16 * MB);  // [B,H,dh,M]
    u16* at_bf = (u16*)(ws + 24 * MB);  // [8192][512]
    u16* wq_t  = (u16*)(ws + 32 * MB);
    u16* wk_t  = (u16*)(ws + 32 * MB + 512 * 1024);
    u16* wv_t  = (u16*)(ws + 33 * MB);
    u16* wo_t  = (u16*)(ws + 33 * MB + 512 * 1024);

    dim3 wg(32, 32, 4);
    wtrans4<<<wg, 256, 0, stream>>>(Wq, Wk, Wv, Wo, wq_t, wk_t, wv_t, wo_t);

    dim3 qkvg(64, 8, 3);
    gemm_qkv<<<qkvg, 256, 0, stream>>>(hidden, enc, wq_t, wk_t, wv_t, q_bf, k_bf, vt_bf);

    flash_attn<<<512, 256, 0, stream>>>(q_bf, k_bf, vt_bf, at_bf);

    dim3 og(64, 8);
    gemm_out<<<og, 256, 0, stream>>>(at_bf, wo_t, bo, out);
}

// Round 5
// 111.247 us; speedup vs baseline: 1.6202x; 1.6202x over previous
//
#include <hip/hip_runtime.h>
#include <stdint.h>
#include <stddef.h>

typedef __bf16 bf16x8 __attribute__((ext_vector_type(8)));
typedef float f32x4 __attribute__((ext_vector_type(4)));
typedef float f32x16 __attribute__((ext_vector_type(16)));
typedef int int4v __attribute__((ext_vector_type(4)));
typedef unsigned short u16;
typedef unsigned int u32;

__device__ __forceinline__ u16 f2bf(float f) {
    union { float f; unsigned u; } x; x.f = f;
    unsigned r = x.u + 0x7fffu + ((x.u >> 16) & 1u);
    return (u16)(r >> 16);
}

__device__ __forceinline__ float fexp2(float x) { return __builtin_amdgcn_exp2f(x); }

__device__ __forceinline__ u32 cvtpk(float lo, float hi) {
    u32 r;
    asm("v_cvt_pk_bf16_f32 %0, %1, %2" : "=v"(r) : "v"(lo), "v"(hi));
    return r;
}

__device__ __forceinline__ void perm32swap(u32& a, u32& b) {
    asm("v_permlane32_swap_b32 %0, %1" : "+v"(a), "+v"(b));
}

__device__ __forceinline__ f32x16 mfma32(bf16x8 a, bf16x8 b, f32x16 c) {
    return __builtin_amdgcn_mfma_f32_32x32x16_bf16(a, b, c, 0, 0, 0);
}

// ---------- all 4 weight transposes in one launch ----------
__global__ __launch_bounds__(256) void wtrans4(
        const float* __restrict__ Wq, const float* __restrict__ Wk,
        const float* __restrict__ Wv, const float* __restrict__ Wo,
        u16* __restrict__ oq, u16* __restrict__ ok,
        u16* __restrict__ ov, u16* __restrict__ oo) {
    const int z = blockIdx.z;
    const float* W = (z == 0) ? Wq : (z == 1) ? Wk : (z == 2) ? Wv : Wo;
    u16* O = (z == 0) ? oq : (z == 1) ? ok : (z == 2) ? ov : oo;
    int n = blockIdx.x * 16 + (threadIdx.x >> 4);
    int k = blockIdx.y * 16 + (threadIdx.x & 15);
    O[(size_t)n * 512 + k] = f2bf(W[(size_t)k * 512 + n]);
}

// ---------- fused QKV GEMM ----------
__global__ __launch_bounds__(256) void gemm_qkv(
        const float* __restrict__ hidden, const float* __restrict__ enc,
        const u16* __restrict__ wq, const u16* __restrict__ wk, const u16* __restrict__ wv,
        u16* __restrict__ qo, u16* __restrict__ ko, u16* __restrict__ vo) {
    __shared__ __align__(16) u16 As[128 * 64];
    __shared__ __align__(16) u16 Bs[64 * 64];
    const int z = blockIdx.z;
    const float* A = (z == 0) ? hidden : enc;
    const u16* Bt = (z == 0) ? wq : (z == 1) ? wk : wv;
    const int tid = threadIdx.x, lane = tid & 63, wave = tid >> 6;
    const int wr = (wave >> 1) * 64, wc = (wave & 1) * 32;
    const int brow = blockIdx.x * 128, bcol = blockIdx.y * 64;
    const int lrow = lane & 15;

    f32x4 acc[4][2] = {};

    for (int k0 = 0; k0 < 512; k0 += 64) {
#pragma unroll
        for (int i = 0; i < 4; ++i) {
            int g = i * 256 + tid;
            int r = g >> 3, gc = g & 7;
            const float* src = A + (size_t)(brow + r) * 512 + k0 + gc * 8;
            float4 f0 = *(const float4*)src, f1 = *(const float4*)(src + 4);
            int4v w;
            w[0] = cvtpk(f0.x, f0.y); w[1] = cvtpk(f0.z, f0.w);
            w[2] = cvtpk(f1.x, f1.y); w[3] = cvtpk(f1.z, f1.w);
            *(int4v*)((char*)As + r * 128 + ((gc ^ (r & 7)) << 4)) = w;
        }
#pragma unroll
        for (int i = 0; i < 2; ++i) {
            int g = i * 256 + tid;
            int r = g >> 3, gc = g & 7;
            const u16* src = Bt + (size_t)(bcol + r) * 512 + k0 + gc * 8;
            *(int4v*)((char*)Bs + r * 128 + ((gc ^ (r & 7)) << 4)) = *(const int4v*)src;
        }
        __syncthreads();
#pragma unroll
        for (int kc = 0; kc < 2; ++kc) {
            const int kg = kc * 4 + (lane >> 4);
            bf16x8 af[4], bfr[2];
#pragma unroll
            for (int m = 0; m < 4; ++m) {
                int r = wr + m * 16 + lrow;
                af[m] = *(const bf16x8*)((char*)As + r * 128 + ((kg ^ (r & 7)) << 4));
            }
#pragma unroll
            for (int n = 0; n < 2; ++n) {
                int r = wc + n * 16 + lrow;
                bfr[n] = *(const bf16x8*)((char*)Bs + r * 128 + ((kg ^ (r & 7)) << 4));
            }
#pragma unroll
            for (int m = 0; m < 4; ++m)
#pragma unroll
                for (int n = 0; n < 2; ++n)
                    acc[m][n] = __builtin_amdgcn_mfma_f32_16x16x32_bf16(af[m], bfr[n], acc[m][n], 0, 0, 0);
        }
        __syncthreads();
    }

#pragma unroll
    for (int m = 0; m < 4; ++m) {
        int gr0 = brow + wr + m * 16 + ((lane >> 4) << 2);
#pragma unroll
        for (int n = 0; n < 2; ++n) {
            int gc = bcol + wc + n * 16 + lrow;
            int hh = gc >> 6, d = gc & 63;
            if (z == 2) {
                int b = gr0 >> 11, mm = gr0 & 2047;
                ushort4 pk;
                pk.x = f2bf(acc[m][n][0]); pk.y = f2bf(acc[m][n][1]);
                pk.z = f2bf(acc[m][n][2]); pk.w = f2bf(acc[m][n][3]);
                *(ushort4*)(vo + ((size_t)(b * 8 + hh) * 64 + d) * 2048 + mm) = pk;
            } else {
                u16* dst = (z == 0) ? qo : ko;
                const float s = (z == 0) ? 0.125f * 1.44269504f : 1.0f;
#pragma unroll
                for (int j = 0; j < 4; ++j) {
                    int gr = gr0 + j;
                    int b = gr >> 11, nn = gr & 2047;
                    dst[((size_t)(b * 8 + hh) * 2048 + nn) * 64 + d] = f2bf(acc[m][n][j] * s);
                }
            }
        }
    }
}

// ---------- output GEMM: out[8192][512] = at_bf @ Wo^T + bo ----------
__global__ __launch_bounds__(256) void gemm_out(
        const u16* __restrict__ A, const u16* __restrict__ Bt,
        const float* __restrict__ bias, float* __restrict__ out) {
    __shared__ __align__(16) u16 As[128 * 64];
    __shared__ __align__(16) u16 Bs[64 * 64];
    const int tid = threadIdx.x, lane = tid & 63, wave = tid >> 6;
    const int wr = (wave >> 1) * 64, wc = (wave & 1) * 32;
    const int brow = blockIdx.x * 128, bcol = blockIdx.y * 64;
    const int lrow = lane & 15;

    f32x4 acc[4][2] = {};

    for (int k0 = 0; k0 < 512; k0 += 64) {
#pragma unroll
        for (int i = 0; i < 4; ++i) {
            int g = i * 256 + tid;
            int r = g >> 3, gc = g & 7;
            const u16* src = A + (size_t)(brow + r) * 512 + k0 + gc * 8;
            *(int4v*)((char*)As + r * 128 + ((gc ^ (r & 7)) << 4)) = *(const int4v*)src;
        }
#pragma unroll
        for (int i = 0; i < 2; ++i) {
            int g = i * 256 + tid;
            int r = g >> 3, gc = g & 7;
            const u16* src = Bt + (size_t)(bcol + r) * 512 + k0 + gc * 8;
            *(int4v*)((char*)Bs + r * 128 + ((gc ^ (r & 7)) << 4)) = *(const int4v*)src;
        }
        __syncthreads();
#pragma unroll
        for (int kc = 0; kc < 2; ++kc) {
            const int kg = kc * 4 + (lane >> 4);
            bf16x8 af[4], bfr[2];
#pragma unroll
            for (int m = 0; m < 4; ++m) {
                int r = wr + m * 16 + lrow;
                af[m] = *(const bf16x8*)((char*)As + r * 128 + ((kg ^ (r & 7)) << 4));
            }
#pragma unroll
            for (int n = 0; n < 2; ++n) {
                int r = wc + n * 16 + lrow;
                bfr[n] = *(const bf16x8*)((char*)Bs + r * 128 + ((kg ^ (r & 7)) << 4));
            }
#pragma unroll
            for (int m = 0; m < 4; ++m)
#pragma unroll
                for (int n = 0; n < 2; ++n)
                    acc[m][n] = __builtin_amdgcn_mfma_f32_16x16x32_bf16(af[m], bfr[n], acc[m][n], 0, 0, 0);
        }
        __syncthreads();
    }

#pragma unroll
    for (int m = 0; m < 4; ++m) {
        int gr0 = brow + wr + m * 16 + ((lane >> 4) << 2);
#pragma unroll
        for (int n = 0; n < 2; ++n) {
            int gc = bcol + wc + n * 16 + lrow;
            float bv = bias[gc];
#pragma unroll
            for (int j = 0; j < 4; ++j)
                out[(size_t)(gr0 + j) * 512 + gc] = acc[m][n][j] + bv;
        }
    }
}

// ---------- flash attention v5: split-KV, LDS-shared staging ----------
// 1024 blocks x 256 thr (4 waves). Wave w: q-subtile (w>>1), KV half (w&1).
// Each block: 64 q-rows; two waves per q-subtile accumulate disjoint KV halves,
// combined exactly at the end via LDS (unnormalized no-max softmax).
// Per step: LDS holds K/V 64-tiles for BOTH halves (32KB, single buffer).
__global__ __launch_bounds__(256) void flash_attn(
        const u16* __restrict__ Q, const u16* __restrict__ K,
        const u16* __restrict__ VT, u16* __restrict__ Oa) {
    __shared__ __align__(16) u16 Ks[2][64 * 64];
    __shared__ __align__(16) u16 Vs[2][64 * 64];

    const int tid  = threadIdx.x;
    const int lane = tid & 63;
    const int wave = tid >> 6;
    const int bid  = blockIdx.x;
    const int lid  = (bid & 7) * 128 + (bid >> 3);   // bijective XCD swizzle (1024 = 8*128)
    const int bh   = lid >> 5;                        // 0..31
    const int qt   = lid & 31;                        // 0..31 (q-tiles of 64)
    const int ql   = lane & 31;
    const int hl   = lane >> 5;
    const int qsub = wave >> 1;                       // 0/1
    const int half = wave & 1;                        // KV half
    const int qg   = qt * 64 + qsub * 32 + ql;

    // Q b-frags (pre-scaled by 0.125*log2e in gemm_qkv)
    const u16* qp = Q + ((size_t)bh * 2048 + qg) * 64 + 8 * hl;
    bf16x8 qf[4];
#pragma unroll
    for (int kc = 0; kc < 4; ++kc) qf[kc] = *(const bf16x8*)(qp + 16 * kc);

    // staging: each thread stages 2 granules (rows srow, srow+32) of all 4 tiles
    const int srow = tid >> 3, scol = tid & 7;        // srow 0..31
    const int ld0 = srow * 128 + ((scol ^ (srow & 7)) << 4);
    const int ld1 = ld0 + 32 * 128;                   // (srow+32)&7 == srow&7
    const u16* K0b = K  + ((size_t)bh * 2048 + 0   ) * 64;
    const u16* K1b = K  + ((size_t)bh * 2048 + 1024) * 64;
    const u16* V0b = VT + ((size_t)bh * 64) * 2048;
    const u16* V1b = V0b + 1024;

    int4v k0r0, k0r1, k1r0, k1r1, v0r0, v0r1, v1r0, v1r1;

#define LD(T) do { \
    k0r0 = *(const int4v*)(K0b + (size_t)((T) * 64 + srow)      * 64 + scol * 8); \
    k0r1 = *(const int4v*)(K0b + (size_t)((T) * 64 + srow + 32) * 64 + scol * 8); \
    k1r0 = *(const int4v*)(K1b + (size_t)((T) * 64 + srow)      * 64 + scol * 8); \
    k1r1 = *(const int4v*)(K1b + (size_t)((T) * 64 + srow + 32) * 64 + scol * 8); \
    v0r0 = *(const int4v*)(V0b + (size_t)srow        * 2048 + (T) * 64 + scol * 8); \
    v0r1 = *(const int4v*)(V0b + (size_t)(srow + 32) * 2048 + (T) * 64 + scol * 8); \
    v1r0 = *(const int4v*)(V1b + (size_t)srow        * 2048 + (T) * 64 + scol * 8); \
    v1r1 = *(const int4v*)(V1b + (size_t)(srow + 32) * 2048 + (T) * 64 + scol * 8); \
} while (0)

#define ST() do { \
    *(int4v*)((char*)Ks[0] + ld0) = k0r0; *(int4v*)((char*)Ks[0] + ld1) = k0r1; \
    *(int4v*)((char*)Ks[1] + ld0) = k1r0; *(int4v*)((char*)Ks[1] + ld1) = k1r1; \
    *(int4v*)((char*)Vs[0] + ld0) = v0r0; *(int4v*)((char*)Vs[0] + ld1) = v0r1; \
    *(int4v*)((char*)Vs[1] + ld0) = v1r0; *(int4v*)((char*)Vs[1] + ld1) = v1r1; \
} while (0)

    f32x16 acc0 = {}, acc1 = {};
    float ls0 = 0.f, ls1 = 0.f, ls2 = 0.f, ls3 = 0.f;

    const char* Kh = (const char*)Ks[half];
    const char* Vh = (const char*)Vs[half];

    LD(0);
    ST();
    __syncthreads();

    for (int t = 0; t < 16; ++t) {
        if (t < 15) LD(t + 1);   // in-flight during compute (T14)

        // ST = K . Q^T
        f32x16 st0 = {}, st1 = {};
        __builtin_amdgcn_s_setprio(1);
#pragma unroll
        for (int kc = 0; kc < 4; ++kc) {
            const int sg = (2 * kc + hl) ^ (ql & 7);
            bf16x8 ka = *(const bf16x8*)(Kh + ql * 128 + (sg << 4));
            bf16x8 kb = *(const bf16x8*)(Kh + (32 + ql) * 128 + (sg << 4));
            st0 = mfma32(ka, qf[kc], st0);
            st1 = mfma32(kb, qf[kc], st1);
        }
        __builtin_amdgcn_s_setprio(0);

        // p = exp2(st); running row-sums
#pragma unroll
        for (int r = 0; r < 16; r += 4) {
            st0[r]   = fexp2(st0[r]);   ls0 += st0[r];
            st0[r+1] = fexp2(st0[r+1]); ls1 += st0[r+1];
            st0[r+2] = fexp2(st0[r+2]); ls2 += st0[r+2];
            st0[r+3] = fexp2(st0[r+3]); ls3 += st0[r+3];
        }
#pragma unroll
        for (int r = 0; r < 16; r += 4) {
            st1[r]   = fexp2(st1[r]);   ls0 += st1[r];
            st1[r+1] = fexp2(st1[r+1]); ls1 += st1[r+1];
            st1[r+2] = fexp2(st1[r+2]); ls2 += st1[r+2];
            st1[r+3] = fexp2(st1[r+3]); ls3 += st1[r+3];
        }

        // O^T += VT . P^T
#define PP(i) ((i) < 16 ? st0[(i) & 15] : st1[(i) & 15])
        __builtin_amdgcn_s_setprio(1);
#pragma unroll
        for (int kc = 0; kc < 4; ++kc) {
            u32 A0 = cvtpk(PP(8 * kc + 0), PP(8 * kc + 1));
            u32 A1 = cvtpk(PP(8 * kc + 2), PP(8 * kc + 3));
            u32 B0 = cvtpk(PP(8 * kc + 4), PP(8 * kc + 5));
            u32 B1 = cvtpk(PP(8 * kc + 6), PP(8 * kc + 7));
            perm32swap(A0, B0);
            perm32swap(A1, B1);
            union { bf16x8 v; u32 u[4]; } bb;
            bb.u[0] = A0; bb.u[1] = A1; bb.u[2] = B0; bb.u[3] = B1;
            const int sg = (2 * kc + hl) ^ (ql & 7);
            bf16x8 va = *(const bf16x8*)(Vh + ql * 128 + (sg << 4));
            bf16x8 vb = *(const bf16x8*)(Vh + (32 + ql) * 128 + (sg << 4));
            acc0 = mfma32(va, bb.v, acc0);
            acc1 = mfma32(vb, bb.v, acc1);
        }
        __builtin_amdgcn_s_setprio(0);
#undef PP

        __syncthreads();          // all waves done reading LDS
        if (t < 15) {
            ST();                 // write next tile (vmcnt-waited automatically)
            __syncthreads();
        }
    }
#undef LD
#undef ST

    // own lsum (lane pair ql / ql+32 hold disjoint kv subsets)
    float lsum = (ls0 + ls1) + (ls2 + ls3);
    lsum += __shfl_xor(lsum, 32);

    // cross-wave combine: waves 1,3 publish; waves 0,2 reduce+store
    float* reg = (wave & 2) ? (float*)Vs : (float*)Ks;  // per q-subtile region
    if (half == 1) {
#pragma unroll
        for (int j = 0; j < 4; ++j)
            *(f32x4*)(reg + lane * 32 + ((j ^ (lane & 7)) << 2)) =
                f32x4{acc0[4*j], acc0[4*j+1], acc0[4*j+2], acc0[4*j+3]};
#pragma unroll
        for (int j = 0; j < 4; ++j)
            *(f32x4*)(reg + lane * 32 + (((j + 4) ^ (lane & 7)) << 2)) =
                f32x4{acc1[4*j], acc1[4*j+1], acc1[4*j+2], acc1[4*j+3]};
        reg[2048 + lane] = lsum;
    }
    __syncthreads();
    if (half == 0) {
#pragma unroll
        for (int j = 0; j < 4; ++j) {
            f32x4 p = *(const f32x4*)(reg + lane * 32 + ((j ^ (lane & 7)) << 2));
            acc0[4*j] += p[0]; acc0[4*j+1] += p[1]; acc0[4*j+2] += p[2]; acc0[4*j+3] += p[3];
        }
#pragma unroll
        for (int j = 0; j < 4; ++j) {
            f32x4 p = *(const f32x4*)(reg + lane * 32 + (((j + 4) ^ (lane & 7)) << 2));
            acc1[4*j] += p[0]; acc1[4*j+1] += p[1]; acc1[4*j+2] += p[2]; acc1[4*j+3] += p[3];
        }
        lsum += reg[2048 + lane];
        float inv = 1.0f / lsum;

        // O^T[d][q]: q = lane&31, d = 32*db + 8*rg + 4*hl + (reg&3)
        int b = bh >> 3, hd = bh & 7;
        u16* orow = Oa + ((size_t)b * 2048 + qg) * 512 + hd * 64;
#pragma unroll
        for (int db = 0; db < 2; ++db) {
            const f32x16 a = db ? acc1 : acc0;
#pragma unroll
            for (int rg = 0; rg < 4; ++rg) {
                int d0 = db * 32 + rg * 8 + hl * 4;
                ushort4 pk;
                pk.x = f2bf(a[rg * 4 + 0] * inv);
                pk.y = f2bf(a[rg * 4 + 1] * inv);
                pk.z = f2bf(a[rg * 4 + 2] * inv);
                pk.w = f2bf(a[rg * 4 + 3] * inv);
                *(ushort4*)(orow + d0) = pk;
            }
        }
    }
}

extern "C" void kernel_launch(void* const* d_in, const int* in_sizes, int n_in,
                              void* d_out, int out_size, void* d_ws, size_t ws_size,
                              hipStream_t stream) {
    const float* hidden = (const float*)d_in[0];
    const float* enc    = (const float*)d_in[1];
    const float* Wq     = (const float*)d_in[2];
    const float* Wk     = (const float*)d_in[3];
    const float* Wv     = (const float*)d_in[4];
    const float* Wo     = (const float*)d_in[5];
    const float* bo     = (const float*)d_in[6];
    float* out = (float*)d_out;

    char* ws = (char*)d_ws;
    const size_t MB = 1ull << 20;
    u16* q_bf  = (u16*)(ws + 0 * MB);   // [B,H,N,dh] (pre-scaled 0.125*log2e)
    u16* k_bf  = (u16*)(ws + 8 * MB);   // [B,H,M,dh]
    u16* vt_bf = (u16*)(ws + 16 * MB);  // [B,H,dh,M]
    u16* at_bf = (u16*)(ws + 24 * MB);  // [8192][512]
    u16* wq_t  = (u16*)(ws + 32 * MB);
    u16* wk_t  = (u16*)(ws + 32 * MB + 512 * 1024);
    u16* wv_t  = (u16*)(ws + 33 * MB);
    u16* wo_t  = (u16*)(ws + 33 * MB + 512 * 1024);

    dim3 wg(32, 32, 4);
    wtrans4<<<wg, 256, 0, stream>>>(Wq, Wk, Wv, Wo, wq_t, wk_t, wv_t, wo_t);

    dim3 qkvg(64, 8, 3);
    gemm_qkv<<<qkvg, 256, 0, stream>>>(hidden, enc, wq_t, wk_t, wv_t, q_bf, k_bf, vt_bf);

    flash_attn<<<1024, 256, 0, stream>>>(q_bf, k_bf, vt_bf, at_bf);

    dim3 og(64, 8);
    gemm_out<<<og, 256, 0, stream>>>(at_bf, wo_t, bo, out);
}

// Round 6
// 107.133 us; speedup vs baseline: 1.6824x; 1.0384x over previous
//
#include <hip/hip_runtime.h>
#include <stdint.h>
#include <stddef.h>

typedef __bf16 bf16x8 __attribute__((ext_vector_type(8)));
typedef float f32x4 __attribute__((ext_vector_type(4)));
typedef float f32x16 __attribute__((ext_vector_type(16)));
typedef int int4v __attribute__((ext_vector_type(4)));
typedef unsigned short u16;
typedef unsigned int u32;

__device__ __forceinline__ u16 f2bf(float f) {
    union { float f; unsigned u; } x; x.f = f;
    unsigned r = x.u + 0x7fffu + ((x.u >> 16) & 1u);
    return (u16)(r >> 16);
}

__device__ __forceinline__ float fexp2(float x) { return __builtin_amdgcn_exp2f(x); }

__device__ __forceinline__ u32 cvtpk(float lo, float hi) {
    u32 r;
    asm("v_cvt_pk_bf16_f32 %0, %1, %2" : "=v"(r) : "v"(lo), "v"(hi));
    return r;
}

__device__ __forceinline__ void perm32swap(u32& a, u32& b) {
    asm("v_permlane32_swap_b32 %0, %1" : "+v"(a), "+v"(b));
}

__device__ __forceinline__ f32x16 mfma32(bf16x8 a, bf16x8 b, f32x16 c) {
    return __builtin_amdgcn_mfma_f32_32x32x16_bf16(a, b, c, 0, 0, 0);
}

// async global->LDS, 16B per lane, wave-uniform LDS base + lane*16
__device__ __forceinline__ void gl16(const void* g, void* l) {
    __builtin_amdgcn_global_load_lds(
        (const __attribute__((address_space(1))) void*)g,
        (__attribute__((address_space(3))) void*)l, 16, 0, 0);
}

// ---------- all 4 weight transposes in one launch ----------
__global__ __launch_bounds__(256) void wtrans4(
        const float* __restrict__ Wq, const float* __restrict__ Wk,
        const float* __restrict__ Wv, const float* __restrict__ Wo,
        u16* __restrict__ oq, u16* __restrict__ ok,
        u16* __restrict__ ov, u16* __restrict__ oo) {
    const int z = blockIdx.z;
    const float* W = (z == 0) ? Wq : (z == 1) ? Wk : (z == 2) ? Wv : Wo;
    u16* O = (z == 0) ? oq : (z == 1) ? ok : (z == 2) ? ov : oo;
    int n = blockIdx.x * 16 + (threadIdx.x >> 4);
    int k = blockIdx.y * 16 + (threadIdx.x & 15);
    O[(size_t)n * 512 + k] = f2bf(W[(size_t)k * 512 + n]);
}

// ---------- fused QKV GEMM ----------
__global__ __launch_bounds__(256) void gemm_qkv(
        const float* __restrict__ hidden, const float* __restrict__ enc,
        const u16* __restrict__ wq, const u16* __restrict__ wk, const u16* __restrict__ wv,
        u16* __restrict__ qo, u16* __restrict__ ko, u16* __restrict__ vo) {
    __shared__ __align__(16) u16 As[128 * 64];
    __shared__ __align__(16) u16 Bs[64 * 64];
    const int z = blockIdx.z;
    const float* A = (z == 0) ? hidden : enc;
    const u16* Bt = (z == 0) ? wq : (z == 1) ? wk : wv;
    const int tid = threadIdx.x, lane = tid & 63, wave = tid >> 6;
    const int wr = (wave >> 1) * 64, wc = (wave & 1) * 32;
    const int brow = blockIdx.x * 128, bcol = blockIdx.y * 64;
    const int lrow = lane & 15;

    f32x4 acc[4][2] = {};

    for (int k0 = 0; k0 < 512; k0 += 64) {
#pragma unroll
        for (int i = 0; i < 4; ++i) {
            int g = i * 256 + tid;
            int r = g >> 3, gc = g & 7;
            const float* src = A + (size_t)(brow + r) * 512 + k0 + gc * 8;
            float4 f0 = *(const float4*)src, f1 = *(const float4*)(src + 4);
            int4v w;
            w[0] = cvtpk(f0.x, f0.y); w[1] = cvtpk(f0.z, f0.w);
            w[2] = cvtpk(f1.x, f1.y); w[3] = cvtpk(f1.z, f1.w);
            *(int4v*)((char*)As + r * 128 + ((gc ^ (r & 7)) << 4)) = w;
        }
#pragma unroll
        for (int i = 0; i < 2; ++i) {
            int g = i * 256 + tid;
            int r = g >> 3, gc = g & 7;
            const u16* src = Bt + (size_t)(bcol + r) * 512 + k0 + gc * 8;
            *(int4v*)((char*)Bs + r * 128 + ((gc ^ (r & 7)) << 4)) = *(const int4v*)src;
        }
        __syncthreads();
#pragma unroll
        for (int kc = 0; kc < 2; ++kc) {
            const int kg = kc * 4 + (lane >> 4);
            bf16x8 af[4], bfr[2];
#pragma unroll
            for (int m = 0; m < 4; ++m) {
                int r = wr + m * 16 + lrow;
                af[m] = *(const bf16x8*)((char*)As + r * 128 + ((kg ^ (r & 7)) << 4));
            }
#pragma unroll
            for (int n = 0; n < 2; ++n) {
                int r = wc + n * 16 + lrow;
                bfr[n] = *(const bf16x8*)((char*)Bs + r * 128 + ((kg ^ (r & 7)) << 4));
            }
#pragma unroll
            for (int m = 0; m < 4; ++m)
#pragma unroll
                for (int n = 0; n < 2; ++n)
                    acc[m][n] = __builtin_amdgcn_mfma_f32_16x16x32_bf16(af[m], bfr[n], acc[m][n], 0, 0, 0);
        }
        __syncthreads();
    }

#pragma unroll
    for (int m = 0; m < 4; ++m) {
        int gr0 = brow + wr + m * 16 + ((lane >> 4) << 2);
#pragma unroll
        for (int n = 0; n < 2; ++n) {
            int gc = bcol + wc + n * 16 + lrow;
            int hh = gc >> 6, d = gc & 63;
            if (z == 2) {
                int b = gr0 >> 11, mm = gr0 & 2047;
                ushort4 pk;
                pk.x = f2bf(acc[m][n][0]); pk.y = f2bf(acc[m][n][1]);
                pk.z = f2bf(acc[m][n][2]); pk.w = f2bf(acc[m][n][3]);
                *(ushort4*)(vo + ((size_t)(b * 8 + hh) * 64 + d) * 2048 + mm) = pk;
            } else {
                u16* dst = (z == 0) ? qo : ko;
                const float s = (z == 0) ? 0.125f * 1.44269504f : 1.0f;
#pragma unroll
                for (int j = 0; j < 4; ++j) {
                    int gr = gr0 + j;
                    int b = gr >> 11, nn = gr & 2047;
                    dst[((size_t)(b * 8 + hh) * 2048 + nn) * 64 + d] = f2bf(acc[m][n][j] * s);
                }
            }
        }
    }
}

// ---------- output GEMM: out[8192][512] = at_bf @ Wo^T + bo ----------
__global__ __launch_bounds__(256) void gemm_out(
        const u16* __restrict__ A, const u16* __restrict__ Bt,
        const float* __restrict__ bias, float* __restrict__ out) {
    __shared__ __align__(16) u16 As[128 * 64];
    __shared__ __align__(16) u16 Bs[64 * 64];
    const int tid = threadIdx.x, lane = tid & 63, wave = tid >> 6;
    const int wr = (wave >> 1) * 64, wc = (wave & 1) * 32;
    const int brow = blockIdx.x * 128, bcol = blockIdx.y * 64;
    const int lrow = lane & 15;

    f32x4 acc[4][2] = {};

    for (int k0 = 0; k0 < 512; k0 += 64) {
#pragma unroll
        for (int i = 0; i < 4; ++i) {
            int g = i * 256 + tid;
            int r = g >> 3, gc = g & 7;
            const u16* src = A + (size_t)(brow + r) * 512 + k0 + gc * 8;
            *(int4v*)((char*)As + r * 128 + ((gc ^ (r & 7)) << 4)) = *(const int4v*)src;
        }
#pragma unroll
        for (int i = 0; i < 2; ++i) {
            int g = i * 256 + tid;
            int r = g >> 3, gc = g & 7;
            const u16* src = Bt + (size_t)(bcol + r) * 512 + k0 + gc * 8;
            *(int4v*)((char*)Bs + r * 128 + ((gc ^ (r & 7)) << 4)) = *(const int4v*)src;
        }
        __syncthreads();
#pragma unroll
        for (int kc = 0; kc < 2; ++kc) {
            const int kg = kc * 4 + (lane >> 4);
            bf16x8 af[4], bfr[2];
#pragma unroll
            for (int m = 0; m < 4; ++m) {
                int r = wr + m * 16 + lrow;
                af[m] = *(const bf16x8*)((char*)As + r * 128 + ((kg ^ (r & 7)) << 4));
            }
#pragma unroll
            for (int n = 0; n < 2; ++n) {
                int r = wc + n * 16 + lrow;
                bfr[n] = *(const bf16x8*)((char*)Bs + r * 128 + ((kg ^ (r & 7)) << 4));
            }
#pragma unroll
            for (int m = 0; m < 4; ++m)
#pragma unroll
                for (int n = 0; n < 2; ++n)
                    acc[m][n] = __builtin_amdgcn_mfma_f32_16x16x32_bf16(af[m], bfr[n], acc[m][n], 0, 0, 0);
        }
        __syncthreads();
    }

#pragma unroll
    for (int m = 0; m < 4; ++m) {
        int gr0 = brow + wr + m * 16 + ((lane >> 4) << 2);
#pragma unroll
        for (int n = 0; n < 2; ++n) {
            int gc = bcol + wc + n * 16 + lrow;
            float bv = bias[gc];
#pragma unroll
            for (int j = 0; j < 4; ++j)
                out[(size_t)(gr0 + j) * 512 + gc] = acc[m][n][j] + bv;
        }
    }
}

// ---------- flash attention v6: split-KV-4, 16-wave block, gload_lds dbuf ----------
// 512 blocks x 1024 thr (16 waves = 4 qgrp x 4 kv-quarter). QBLK=128/block, 32q/wave.
// KVBLK=32 per quarter per step; 16 steps; one barrier per step (dbuf).
// Staging: global_load_lds w/ pre-swizzled global source -> linear LDS; reads use
// the same involution: K granule c^=(r&7), V granule c^=((d>>1)&3).
// No-max softmax (log2e folded into Q); exact 4-way combine via LDS at the end.
__global__ __launch_bounds__(1024, 4) void flash_attn(
        const u16* __restrict__ Q, const u16* __restrict__ K,
        const u16* __restrict__ VT, u16* __restrict__ Oa) {
    __shared__ __align__(16) char smem[65536];  // dbuf: 2 x (K 16KB + V 16KB)

    const int tid  = threadIdx.x;
    const int lane = tid & 63;
    const int wave = tid >> 6;          // 0..15
    const int qgrp = wave >> 2;         // 0..3
    const int qtr  = wave & 3;          // kv quarter 0..3
    const int ql   = lane & 31;
    const int hl   = lane >> 5;
    const int bid  = blockIdx.x;
    const int lid  = (bid & 7) * 64 + (bid >> 3);   // bijective XCD swizzle (512=8*64)
    const int bh   = lid >> 4;
    const int qt   = lid & 15;
    const int qg   = qt * 128 + qgrp * 32 + ql;

    // Q b-frags (pre-scaled by 0.125*log2e in gemm_qkv)
    const u16* qp = Q + ((size_t)bh * 2048 + qg) * 64 + 8 * hl;
    bf16x8 qf[4];
#pragma unroll
    for (int kc = 0; kc < 4; ++kc) qf[kc] = *(const bf16x8*)(qp + 16 * kc);

    // staging role: waves 0..7 stage K (quarter w>>1, insts i0,i0+1),
    //               waves 8..15 stage V likewise. 2 gload_lds per wave per step.
    const bool isK = wave < 8;
    const int sq   = isK ? (wave >> 1) : ((wave - 8) >> 1);
    const int i0   = (wave & 1) * 2;
    // pre-swizzled per-lane source offsets (u16 units)
    const int loK = (lane >> 3) * 64 + (((lane & 7) ^ ((lane >> 3) & 7)) * 8);
    const int loV = (lane >> 2) * 2048 + (((lane & 3) ^ ((lane >> 3) & 3)) * 8);
    const u16* gsrc0 = isK
        ? K  + ((size_t)bh * 2048 + sq * 512 + i0 * 8) * 64 + loK
        : VT + (size_t)bh * 131072 + (size_t)(i0 * 16) * 2048 + sq * 512 + loV;
    char* ldst0 = smem + (isK ? 0 : 16384) + sq * 4096 + i0 * 1024;

#define STAGE(b, t) do { \
    const u16* s0_ = gsrc0 + (isK ? (size_t)(t) * 2048 : (size_t)(t) * 32); \
    char* d0_ = ldst0 + (b) * 32768; \
    gl16(s0_, d0_); \
    gl16(s0_ + (isK ? 512 : 32768), d0_ + 1024); \
} while (0)

    f32x16 acc0 = {}, acc1 = {};
    float ls0 = 0.f, ls1 = 0.f, ls2 = 0.f, ls3 = 0.f;

    STAGE(0, 0);
    __syncthreads();   // drains each wave's own gloads; all tiles for t=0 ready

    for (int t = 0; t < 16; ++t) {
        const int b = t & 1;
        if (t < 15) STAGE(b ^ 1, t + 1);   // async, hidden under compute

        const char* Kt = smem + b * 32768 + qtr * 4096;
        const char* Vt = smem + b * 32768 + 16384 + qtr * 4096;

        // ST = K . Q^T  (single 32x32 tile, kv = crow(r,hl))
        f32x16 st = {};
        __builtin_amdgcn_s_setprio(1);
#pragma unroll
        for (int kc = 0; kc < 4; ++kc) {
            bf16x8 kf = *(const bf16x8*)(Kt + ql * 128 + (((kc * 2 + hl) ^ (ql & 7)) << 4));
            st = mfma32(kf, qf[kc], st);
        }
        __builtin_amdgcn_s_setprio(0);

        // p = exp2(st); running row-sums
#pragma unroll
        for (int r = 0; r < 16; r += 4) {
            st[r]   = fexp2(st[r]);   ls0 += st[r];
            st[r+1] = fexp2(st[r+1]); ls1 += st[r+1];
            st[r+2] = fexp2(st[r+2]); ls2 += st[r+2];
            st[r+3] = fexp2(st[r+3]); ls3 += st[r+3];
        }

        // O^T += VT . P^T  (pack P in-register, 2 kc slices of kv16)
        __builtin_amdgcn_s_setprio(1);
#pragma unroll
        for (int kc = 0; kc < 2; ++kc) {
            u32 P0 = cvtpk(st[8 * kc + 0], st[8 * kc + 1]);
            u32 P1 = cvtpk(st[8 * kc + 2], st[8 * kc + 3]);
            u32 Q0 = cvtpk(st[8 * kc + 4], st[8 * kc + 5]);
            u32 Q1 = cvtpk(st[8 * kc + 6], st[8 * kc + 7]);
            perm32swap(P0, Q0);
            perm32swap(P1, Q1);
            union { bf16x8 v; u32 u[4]; } bb;
            bb.u[0] = P0; bb.u[1] = P1; bb.u[2] = Q0; bb.u[3] = Q1;
            const int sg = ((kc * 2 + hl) ^ ((ql >> 1) & 3)) << 4;
            bf16x8 v0 = *(const bf16x8*)(Vt + ql * 64 + sg);
            bf16x8 v1 = *(const bf16x8*)(Vt + (32 + ql) * 64 + sg);
            acc0 = mfma32(v0, bb.v, acc0);
            acc1 = mfma32(v1, bb.v, acc1);
        }
        __builtin_amdgcn_s_setprio(0);

        __syncthreads();   // t+1 loads landed; all reads of buf b done
    }
#undef STAGE

    // per-wave partial row-sum (hl halves hold disjoint kv subsets)
    float lsum = (ls0 + ls1) + (ls2 + ls3);
    lsum += __shfl_xor(lsum, 32);

    // exact 4-way combine: quarters 1..3 publish in 3 phases (reuse staging LDS)
    float* CB = (float*)smem;              // 4 qgrp regions x 2048 floats = 32 KB
    float* LS = (float*)(smem + 32768);    // 4 x 64 lsums
    for (int p = 1; p < 4; ++p) {
        if (qtr == p) {
            float* R = CB + qgrp * 2048;
#pragma unroll
            for (int j = 0; j < 4; ++j)
                *(f32x4*)(R + lane * 32 + ((j ^ (lane & 7)) << 2)) =
                    f32x4{acc0[4*j], acc0[4*j+1], acc0[4*j+2], acc0[4*j+3]};
#pragma unroll
            for (int j = 0; j < 4; ++j)
                *(f32x4*)(R + lane * 32 + (((j + 4) ^ (lane & 7)) << 2)) =
                    f32x4{acc1[4*j], acc1[4*j+1], acc1[4*j+2], acc1[4*j+3]};
            LS[qgrp * 64 + lane] = lsum;
        }
        __syncthreads();
        if (qtr == 0) {
            float* R = CB + qgrp * 2048;
#pragma unroll
            for (int j = 0; j < 4; ++j) {
                f32x4 v = *(const f32x4*)(R + lane * 32 + ((j ^ (lane & 7)) << 2));
                acc0[4*j] += v[0]; acc0[4*j+1] += v[1]; acc0[4*j+2] += v[2]; acc0[4*j+3] += v[3];
            }
#pragma unroll
            for (int j = 0; j < 4; ++j) {
                f32x4 v = *(const f32x4*)(R + lane * 32 + (((j + 4) ^ (lane & 7)) << 2));
                acc1[4*j] += v[0]; acc1[4*j+1] += v[1]; acc1[4*j+2] += v[2]; acc1[4*j+3] += v[3];
            }
            lsum += LS[qgrp * 64 + lane];
        }
        __syncthreads();
    }

    if (qtr == 0) {
        float inv = 1.0f / lsum;
        // O^T[d][q]: q = ql, d = 32*db + 8*rg + 4*hl + j
        int b_ = bh >> 3, hd = bh & 7;
        u16* orow = Oa + ((size_t)b_ * 2048 + qg) * 512 + hd * 64;
#pragma unroll
        for (int db = 0; db < 2; ++db) {
            const f32x16 a = db ? acc1 : acc0;
#pragma unroll
            for (int rg = 0; rg < 4; ++rg) {
                int d0 = db * 32 + rg * 8 + hl * 4;
                ushort4 pk;
                pk.x = f2bf(a[rg * 4 + 0] * inv);
                pk.y = f2bf(a[rg * 4 + 1] * inv);
                pk.z = f2bf(a[rg * 4 + 2] * inv);
                pk.w = f2bf(a[rg * 4 + 3] * inv);
                *(ushort4*)(orow + d0) = pk;
            }
        }
    }
}

extern "C" void kernel_launch(void* const* d_in, const int* in_sizes, int n_in,
                              void* d_out, int out_size, void* d_ws, size_t ws_size,
                              hipStream_t stream) {
    const float* hidden = (const float*)d_in[0];
    const float* enc    = (const float*)d_in[1];
    const float* Wq     = (const float*)d_in[2];
    const float* Wk     = (const float*)d_in[3];
    const float* Wv     = (const float*)d_in[4];
    const float* Wo     = (const float*)d_in[5];
    const float* bo     = (const float*)d_in[6];
    float* out = (float*)d_out;

    char* ws = (char*)d_ws;
    const size_t MB = 1ull << 20;
    u16* q_bf  = (u16*)(ws + 0 * MB);   // [B,H,N,dh] (pre-scaled 0.125*log2e)
    u16* k_bf  = (u16*)(ws + 8 * MB);   // [B,H,M,dh]
    u16* vt_bf = (u16*)(ws + 16 * MB);  // [B,H,dh,M]
    u16* at_bf = (u16*)(ws + 24 * MB);  // [8192][512]
    u16* wq_t  = (u16*)(ws + 32 * MB);
    u16* wk_t  = (u16*)(ws + 32 * MB + 512 * 1024);
    u16* wv_t  = (u16*)(ws + 33 * MB);
    u16* wo_t  = (u16*)(ws + 33 * MB + 512 * 1024);

    dim3 wg(32, 32, 4);
    wtrans4<<<wg, 256, 0, stream>>>(Wq, Wk, Wv, Wo, wq_t, wk_t, wv_t, wo_t);

    dim3 qkvg(64, 8, 3);
    gemm_qkv<<<qkvg, 256, 0, stream>>>(hidden, enc, wq_t, wk_t, wv_t, q_bf, k_bf, vt_bf);

    flash_attn<<<512, 1024, 0, stream>>>(q_bf, k_bf, vt_bf, at_bf);

    dim3 og(64, 8);
    gemm_out<<<og, 256, 0, stream>>>(at_bf, wo_t, bo, out);
}

// Round 7
// 95.344 us; speedup vs baseline: 1.8904x; 1.1236x over previous
//
#include <hip/hip_runtime.h>
#include <stdint.h>
#include <stddef.h>

typedef __bf16 bf16x8 __attribute__((ext_vector_type(8)));
typedef float f32x4 __attribute__((ext_vector_type(4)));
typedef float f32x16 __attribute__((ext_vector_type(16)));
typedef int int4v __attribute__((ext_vector_type(4)));
typedef unsigned short u16;
typedef unsigned int u32;

__device__ __forceinline__ u16 f2bf(float f) {
    union { float f; unsigned u; } x; x.f = f;
    unsigned r = x.u + 0x7fffu + ((x.u >> 16) & 1u);
    return (u16)(r >> 16);
}

__device__ __forceinline__ float fexp2(float x) { return __builtin_amdgcn_exp2f(x); }

__device__ __forceinline__ u32 cvtpk(float lo, float hi) {
    u32 r;
    asm("v_cvt_pk_bf16_f32 %0, %1, %2" : "=v"(r) : "v"(lo), "v"(hi));
    return r;
}

__device__ __forceinline__ void perm32swap(u32& a, u32& b) {
    asm("v_permlane32_swap_b32 %0, %1" : "+v"(a), "+v"(b));
}

__device__ __forceinline__ f32x16 mfma32(bf16x8 a, bf16x8 b, f32x16 c) {
    return __builtin_amdgcn_mfma_f32_32x32x16_bf16(a, b, c, 0, 0, 0);
}

// async global->LDS, 16B/lane: dst wave-uniform base (+lane*16 by HW), src per-lane
__device__ __forceinline__ void gl16(const void* g, void* l) {
    __builtin_amdgcn_global_load_lds(
        (const __attribute__((address_space(1))) void*)g,
        (__attribute__((address_space(3))) void*)l, 16, 0, 0);
}

// ---------- weight transpose+pack: W[512][512] f32 -> W'[k0][n][g'] bf16 ----------
// W' granule (16B = 8 bf16) at index (k0*512 + n)*8 + g', g' = g ^ (n&7),
// holding Wt[n][k0*64 + g*8 .. +8] = W[k][n]. This is the exact swizzled LDS
// tile image so GEMM B-staging is a linear global_load_lds.
__global__ __launch_bounds__(256) void wtrans4(
        const float* __restrict__ Wq, const float* __restrict__ Wk,
        const float* __restrict__ Wv, const float* __restrict__ Wo,
        u16* __restrict__ oq, u16* __restrict__ ok,
        u16* __restrict__ ov, u16* __restrict__ oo) {
    const int z = blockIdx.z;
    const float* W = (z == 0) ? Wq : (z == 1) ? Wk : (z == 2) ? Wv : Wo;
    u16* O = (z == 0) ? oq : (z == 1) ? ok : (z == 2) ? ov : oo;
    int t  = blockIdx.x * 256 + threadIdx.x;   // 0..32767
    int g  = t >> 12;
    int k0 = (t >> 9) & 7;
    int n  = t & 511;
    float v[8];
#pragma unroll
    for (int j = 0; j < 8; ++j)
        v[j] = W[(size_t)(k0 * 64 + g * 8 + j) * 512 + n];
    int gs = g ^ (n & 7);
    u16* dst = O + ((size_t)(k0 * 512 + n) * 8 + gs) * 8;
    ushort4 a, b;
    a.x = f2bf(v[0]); a.y = f2bf(v[1]); a.z = f2bf(v[2]); a.w = f2bf(v[3]);
    b.x = f2bf(v[4]); b.y = f2bf(v[5]); b.z = f2bf(v[6]); b.w = f2bf(v[7]);
    *(ushort4*)dst = a;
    *(ushort4*)(dst + 4) = b;
}

// ---------- fused QKV GEMM: 128x128 tile, BK=64, m97 structure ----------
// grid (64, 4, 3); z: 0=q(hidden), 1=k(enc), 2=v(enc). 4 waves (2x2 of 64x64).
// A: f32 reg-staged + cvt + swizzled ds_write. B: 4x gl16/wave from W' image.
__global__ __launch_bounds__(256) void gemm_qkv(
        const float* __restrict__ hidden, const float* __restrict__ enc,
        const u16* __restrict__ wq, const u16* __restrict__ wk, const u16* __restrict__ wv,
        u16* __restrict__ qo, u16* __restrict__ ko, u16* __restrict__ vo) {
    __shared__ __align__(16) u16 As[128 * 64];
    __shared__ __align__(16) u16 Bs[128 * 64];
    const int z = blockIdx.z;
    const float* A = (z == 0) ? hidden : enc;
    const u16* Bp = (z == 0) ? wq : (z == 1) ? wk : wv;
    const int tid = threadIdx.x, lane = tid & 63, wave = tid >> 6;
    const int wr = (wave >> 1) * 64, wc = (wave & 1) * 64;
    const int brow = blockIdx.x * 128, bcol = blockIdx.y * 128;
    const int lrow = lane & 15;
    const int sr = tid >> 3, sc = tid & 7;    // A staging: row, granule

    f32x4 acc[4][4] = {};

    for (int k0s = 0; k0s < 8; ++k0s) {
        // B: pure async copy of 16KB pre-swizzled image
        const u16* bsrc = Bp + ((size_t)(k0s * 512 + bcol) * 64) + (size_t)(wave * 256 + lane) * 8;
#pragma unroll
        for (int i = 0; i < 4; ++i)
            gl16(bsrc + i * 512, (char*)Bs + wave * 4096 + i * 1024);
        // A: f32 -> bf16 staged (4 granules/thread)
#pragma unroll
        for (int i = 0; i < 4; ++i) {
            int r = i * 32 + sr;
            const float* src = A + (size_t)(brow + r) * 512 + k0s * 64 + sc * 8;
            float4 f0 = *(const float4*)src, f1 = *(const float4*)(src + 4);
            int4v w;
            w[0] = cvtpk(f0.x, f0.y); w[1] = cvtpk(f0.z, f0.w);
            w[2] = cvtpk(f1.x, f1.y); w[3] = cvtpk(f1.z, f1.w);
            *(int4v*)((char*)As + r * 128 + ((sc ^ (r & 7)) << 4)) = w;
        }
        __syncthreads();
#pragma unroll
        for (int kc = 0; kc < 2; ++kc) {
            const int kg = kc * 4 + (lane >> 4);
            bf16x8 af[4], bfr[4];
#pragma unroll
            for (int m = 0; m < 4; ++m) {
                int r = wr + m * 16 + lrow;
                af[m] = *(const bf16x8*)((char*)As + r * 128 + ((kg ^ (r & 7)) << 4));
            }
#pragma unroll
            for (int n = 0; n < 4; ++n) {
                int r = wc + n * 16 + lrow;
                bfr[n] = *(const bf16x8*)((char*)Bs + r * 128 + ((kg ^ (r & 7)) << 4));
            }
#pragma unroll
            for (int m = 0; m < 4; ++m)
#pragma unroll
                for (int n = 0; n < 4; ++n)
                    acc[m][n] = __builtin_amdgcn_mfma_f32_16x16x32_bf16(af[m], bfr[n], acc[m][n], 0, 0, 0);
        }
        __syncthreads();
    }

    // C/D layout: col = lane&15, row = (lane>>4)*4 + reg
#pragma unroll
    for (int m = 0; m < 4; ++m) {
        int gr0 = brow + wr + m * 16 + ((lane >> 4) << 2);
#pragma unroll
        for (int n = 0; n < 4; ++n) {
            int gc = bcol + wc + n * 16 + lrow;
            int hh = gc >> 6, d = gc & 63;
            if (z == 2) {
                int b = gr0 >> 11, mm = gr0 & 2047;
                ushort4 pk;
                pk.x = f2bf(acc[m][n][0]); pk.y = f2bf(acc[m][n][1]);
                pk.z = f2bf(acc[m][n][2]); pk.w = f2bf(acc[m][n][3]);
                *(ushort4*)(vo + ((size_t)(b * 8 + hh) * 64 + d) * 2048 + mm) = pk;
            } else {
                u16* dst = (z == 0) ? qo : ko;
                const float s = (z == 0) ? 0.125f * 1.44269504f : 1.0f;
#pragma unroll
                for (int j = 0; j < 4; ++j) {
                    int gr = gr0 + j;
                    int b = gr >> 11, nn = gr & 2047;
                    dst[((size_t)(b * 8 + hh) * 2048 + nn) * 64 + d] = f2bf(acc[m][n][j] * s);
                }
            }
        }
    }
}

// ---------- output GEMM: out = at @ Wo^T + bo; 128x64 tile ----------
// A (flash output) is stored PRE-SWIZZLED, so both A and B stage via pure gl16.
__global__ __launch_bounds__(256) void gemm_out(
        const u16* __restrict__ A, const u16* __restrict__ Bp,
        const float* __restrict__ bias, float* __restrict__ out) {
    __shared__ __align__(16) u16 As[128 * 64];
    __shared__ __align__(16) u16 Bs[64 * 64];
    const int tid = threadIdx.x, lane = tid & 63, wave = tid >> 6;
    const int wr = (wave >> 1) * 64, wc = (wave & 1) * 32;
    const int brow = blockIdx.x * 128, bcol = blockIdx.y * 64;
    const int lrow = lane & 15;
    const int ar = wave * 32 + (lane >> 3), ag = lane & 7;  // A gather: row, swizzled granule

    f32x4 acc[4][2] = {};

    for (int k0s = 0; k0s < 8; ++k0s) {
        // A: 4 gl16/wave, per-lane gathered source (image already swizzled)
        const u16* asrc = A + (size_t)(brow + ar) * 512 + k0s * 64 + ag * 8;
#pragma unroll
        for (int i = 0; i < 4; ++i)
            gl16(asrc + (size_t)(i * 8) * 512, (char*)As + wave * 4096 + i * 1024);
        // B: 2 gl16/wave, linear from W' image
        const u16* bsrc = Bp + ((size_t)(k0s * 512 + bcol) * 64) + (size_t)(wave * 128 + lane) * 8;
#pragma unroll
        for (int i = 0; i < 2; ++i)
            gl16(bsrc + i * 512, (char*)Bs + wave * 2048 + i * 1024);
        __syncthreads();
#pragma unroll
        for (int kc = 0; kc < 2; ++kc) {
            const int kg = kc * 4 + (lane >> 4);
            bf16x8 af[4], bfr[2];
#pragma unroll
            for (int m = 0; m < 4; ++m) {
                int r = wr + m * 16 + lrow;
                af[m] = *(const bf16x8*)((char*)As + r * 128 + ((kg ^ (r & 7)) << 4));
            }
#pragma unroll
            for (int n = 0; n < 2; ++n) {
                int r = wc + n * 16 + lrow;
                bfr[n] = *(const bf16x8*)((char*)Bs + r * 128 + ((kg ^ (r & 7)) << 4));
            }
#pragma unroll
            for (int m = 0; m < 4; ++m)
#pragma unroll
                for (int n = 0; n < 2; ++n)
                    acc[m][n] = __builtin_amdgcn_mfma_f32_16x16x32_bf16(af[m], bfr[n], acc[m][n], 0, 0, 0);
        }
        __syncthreads();
    }

#pragma unroll
    for (int m = 0; m < 4; ++m) {
        int gr0 = brow + wr + m * 16 + ((lane >> 4) << 2);
#pragma unroll
        for (int n = 0; n < 2; ++n) {
            int gc = bcol + wc + n * 16 + lrow;
            float bv = bias[gc];
#pragma unroll
            for (int j = 0; j < 4; ++j)
                out[(size_t)(gr0 + j) * 512 + gc] = acc[m][n][j] + bv;
        }
    }
}

// ---------- flash attention (r6 structure; O written pre-swizzled) ----------
__global__ __launch_bounds__(1024, 4) void flash_attn(
        const u16* __restrict__ Q, const u16* __restrict__ K,
        const u16* __restrict__ VT, u16* __restrict__ Oa) {
    __shared__ __align__(16) char smem[65536];  // dbuf: 2 x (K 16KB + V 16KB)

    const int tid  = threadIdx.x;
    const int lane = tid & 63;
    const int wave = tid >> 6;          // 0..15
    const int qgrp = wave >> 2;         // 0..3
    const int qtr  = wave & 3;          // kv quarter 0..3
    const int ql   = lane & 31;
    const int hl   = lane >> 5;
    const int bid  = blockIdx.x;
    const int lid  = (bid & 7) * 64 + (bid >> 3);   // bijective XCD swizzle (512=8*64)
    const int bh   = lid >> 4;
    const int qt   = lid & 15;
    const int qg   = qt * 128 + qgrp * 32 + ql;

    // Q b-frags (pre-scaled by 0.125*log2e in gemm_qkv)
    const u16* qp = Q + ((size_t)bh * 2048 + qg) * 64 + 8 * hl;
    bf16x8 qf[4];
#pragma unroll
    for (int kc = 0; kc < 4; ++kc) qf[kc] = *(const bf16x8*)(qp + 16 * kc);

    const bool isK = wave < 8;
    const int sq   = isK ? (wave >> 1) : ((wave - 8) >> 1);
    const int i0   = (wave & 1) * 2;
    const int loK = (lane >> 3) * 64 + (((lane & 7) ^ ((lane >> 3) & 7)) * 8);
    const int loV = (lane >> 2) * 2048 + (((lane & 3) ^ ((lane >> 3) & 3)) * 8);
    const u16* gsrc0 = isK
        ? K  + ((size_t)bh * 2048 + sq * 512 + i0 * 8) * 64 + loK
        : VT + (size_t)bh * 131072 + (size_t)(i0 * 16) * 2048 + sq * 512 + loV;
    char* ldst0 = smem + (isK ? 0 : 16384) + sq * 4096 + i0 * 1024;

#define STAGE(b, t) do { \
    const u16* s0_ = gsrc0 + (isK ? (size_t)(t) * 2048 : (size_t)(t) * 32); \
    char* d0_ = ldst0 + (b) * 32768; \
    gl16(s0_, d0_); \
    gl16(s0_ + (isK ? 512 : 32768), d0_ + 1024); \
} while (0)

    f32x16 acc0 = {}, acc1 = {};
    float ls0 = 0.f, ls1 = 0.f, ls2 = 0.f, ls3 = 0.f;

    STAGE(0, 0);
    __syncthreads();

    for (int t = 0; t < 16; ++t) {
        const int b = t & 1;
        if (t < 15) STAGE(b ^ 1, t + 1);

        const char* Kt = smem + b * 32768 + qtr * 4096;
        const char* Vt = smem + b * 32768 + 16384 + qtr * 4096;

        f32x16 st = {};
        __builtin_amdgcn_s_setprio(1);
#pragma unroll
        for (int kc = 0; kc < 4; ++kc) {
            bf16x8 kf = *(const bf16x8*)(Kt + ql * 128 + (((kc * 2 + hl) ^ (ql & 7)) << 4));
            st = mfma32(kf, qf[kc], st);
        }
        __builtin_amdgcn_s_setprio(0);

#pragma unroll
        for (int r = 0; r < 16; r += 4) {
            st[r]   = fexp2(st[r]);   ls0 += st[r];
            st[r+1] = fexp2(st[r+1]); ls1 += st[r+1];
            st[r+2] = fexp2(st[r+2]); ls2 += st[r+2];
            st[r+3] = fexp2(st[r+3]); ls3 += st[r+3];
        }

        __builtin_amdgcn_s_setprio(1);
#pragma unroll
        for (int kc = 0; kc < 2; ++kc) {
            u32 P0 = cvtpk(st[8 * kc + 0], st[8 * kc + 1]);
            u32 P1 = cvtpk(st[8 * kc + 2], st[8 * kc + 3]);
            u32 Q0 = cvtpk(st[8 * kc + 4], st[8 * kc + 5]);
            u32 Q1 = cvtpk(st[8 * kc + 6], st[8 * kc + 7]);
            perm32swap(P0, Q0);
            perm32swap(P1, Q1);
            union { bf16x8 v; u32 u[4]; } bb;
            bb.u[0] = P0; bb.u[1] = P1; bb.u[2] = Q0; bb.u[3] = Q1;
            const int sg = ((kc * 2 + hl) ^ ((ql >> 1) & 3)) << 4;
            bf16x8 v0 = *(const bf16x8*)(Vt + ql * 64 + sg);
            bf16x8 v1 = *(const bf16x8*)(Vt + (32 + ql) * 64 + sg);
            acc0 = mfma32(v0, bb.v, acc0);
            acc1 = mfma32(v1, bb.v, acc1);
        }
        __builtin_amdgcn_s_setprio(0);

        __syncthreads();
    }
#undef STAGE

    float lsum = (ls0 + ls1) + (ls2 + ls3);
    lsum += __shfl_xor(lsum, 32);

    float* CB = (float*)smem;
    float* LS = (float*)(smem + 32768);
    for (int p = 1; p < 4; ++p) {
        if (qtr == p) {
            float* R = CB + qgrp * 2048;
#pragma unroll
            for (int j = 0; j < 4; ++j)
                *(f32x4*)(R + lane * 32 + ((j ^ (lane & 7)) << 2)) =
                    f32x4{acc0[4*j], acc0[4*j+1], acc0[4*j+2], acc0[4*j+3]};
#pragma unroll
            for (int j = 0; j < 4; ++j)
                *(f32x4*)(R + lane * 32 + (((j + 4) ^ (lane & 7)) << 2)) =
                    f32x4{acc1[4*j], acc1[4*j+1], acc1[4*j+2], acc1[4*j+3]};
            LS[qgrp * 64 + lane] = lsum;
        }
        __syncthreads();
        if (qtr == 0) {
            float* R = CB + qgrp * 2048;
#pragma unroll
            for (int j = 0; j < 4; ++j) {
                f32x4 v = *(const f32x4*)(R + lane * 32 + ((j ^ (lane & 7)) << 2));
                acc0[4*j] += v[0]; acc0[4*j+1] += v[1]; acc0[4*j+2] += v[2]; acc0[4*j+3] += v[3];
            }
#pragma unroll
            for (int j = 0; j < 4; ++j) {
                f32x4 v = *(const f32x4*)(R + lane * 32 + (((j + 4) ^ (lane & 7)) << 2));
                acc1[4*j] += v[0]; acc1[4*j+1] += v[1]; acc1[4*j+2] += v[2]; acc1[4*j+3] += v[3];
            }
            lsum += LS[qgrp * 64 + lane];
        }
        __syncthreads();
    }

    if (qtr == 0) {
        float inv = 1.0f / lsum;
        // pre-swizzled store: granule g=(db*4+rg) goes to position g^(qg&7)
        int b_ = bh >> 3, hd = bh & 7;
        u16* orow = Oa + ((size_t)b_ * 2048 + qg) * 512 + hd * 64;
#pragma unroll
        for (int db = 0; db < 2; ++db) {
            const f32x16 a = db ? acc1 : acc0;
#pragma unroll
            for (int rg = 0; rg < 4; ++rg) {
                int d0 = (((db * 4 + rg) ^ (qg & 7)) << 3) + hl * 4;
                ushort4 pk;
                pk.x = f2bf(a[rg * 4 + 0] * inv);
                pk.y = f2bf(a[rg * 4 + 1] * inv);
                pk.z = f2bf(a[rg * 4 + 2] * inv);
                pk.w = f2bf(a[rg * 4 + 3] * inv);
                *(ushort4*)(orow + d0) = pk;
            }
        }
    }
}

extern "C" void kernel_launch(void* const* d_in, const int* in_sizes, int n_in,
                              void* d_out, int out_size, void* d_ws, size_t ws_size,
                              hipStream_t stream) {
    const float* hidden = (const float*)d_in[0];
    const float* enc    = (const float*)d_in[1];
    const float* Wq     = (const float*)d_in[2];
    const float* Wk     = (const float*)d_in[3];
    const float* Wv     = (const float*)d_in[4];
    const float* Wo     = (const float*)d_in[5];
    const float* bo     = (const float*)d_in[6];
    float* out = (float*)d_out;

    char* ws = (char*)d_ws;
    const size_t MB = 1ull << 20;
    u16* q_bf  = (u16*)(ws + 0 * MB);   // [B,H,N,dh] (pre-scaled 0.125*log2e)
    u16* k_bf  = (u16*)(ws + 8 * MB);   // [B,H,M,dh]
    u16* vt_bf = (u16*)(ws + 16 * MB);  // [B,H,dh,M]
    u16* at_bf = (u16*)(ws + 24 * MB);  // [8192][512] pre-swizzled image
    u16* wq_t  = (u16*)(ws + 32 * MB);
    u16* wk_t  = (u16*)(ws + 32 * MB + 512 * 1024);
    u16* wv_t  = (u16*)(ws + 33 * MB);
    u16* wo_t  = (u16*)(ws + 33 * MB + 512 * 1024);

    dim3 wg(128, 1, 4);
    wtrans4<<<wg, 256, 0, stream>>>(Wq, Wk, Wv, Wo, wq_t, wk_t, wv_t, wo_t);

    dim3 qkvg(64, 4, 3);
    gemm_qkv<<<qkvg, 256, 0, stream>>>(hidden, enc, wq_t, wk_t, wv_t, q_bf, k_bf, vt_bf);

    flash_attn<<<512, 1024, 0, stream>>>(q_bf, k_bf, vt_bf, at_bf);

    dim3 og(64, 8);
    gemm_out<<<og, 256, 0, stream>>>(at_bf, wo_t, bo, out);
}